// Round 1
// baseline (751.126 us; speedup 1.0000x reference)
//
#include <hip/hip_runtime.h>

#define B 32
#define R 2048
#define C 32
#define O 32
#define IN 16

// K1: votes[b][c][r][o] = sum_i vote[r][c][o][i] * x[b][r][i]
// grid (R, C), 256 threads: o = t&31, bq = t>>5; each thread does 4 b's.
__global__ __launch_bounds__(256) void votes_kernel(
    const float* __restrict__ x,     // [B][R][IN]
    const float* __restrict__ vote,  // [R][C][O][IN]
    float* __restrict__ votes)       // [B][C][R][O]
{
  const int r = blockIdx.x;
  const int c = blockIdx.y;
  const int t = threadIdx.x;
  const int o = t & 31;
  const int bq = t >> 5;  // 0..7

  const float4* vrow = reinterpret_cast<const float4*>(
      vote + (((size_t)r * C + c) * O + o) * IN);
  float4 w0 = vrow[0], w1 = vrow[1], w2 = vrow[2], w3 = vrow[3];

#pragma unroll
  for (int j = 0; j < 4; ++j) {
    int b = bq * 4 + j;  // covers 0..31 exactly once
    const float4* xrow = reinterpret_cast<const float4*>(
        x + ((size_t)b * R + r) * IN);
    float4 x0 = xrow[0], x1 = xrow[1], x2 = xrow[2], x3 = xrow[3];
    float acc =
        w0.x * x0.x + w0.y * x0.y + w0.z * x0.z + w0.w * x0.w +
        w1.x * x1.x + w1.y * x1.y + w1.z * x1.z + w1.w * x1.w +
        w2.x * x2.x + w2.y * x2.y + w2.z * x2.z + w2.w * x2.w +
        w3.x * x3.x + w3.y * x3.y + w3.z * x3.z + w3.w * x3.w;
    votes[(((size_t)b * C + c) * R + r) * O + o] = acc;
  }
}

// K2: one block per (b,c). Thread t owns votes rows r=t and r=t+1024 in
// registers; agreement in 2 regs. 3 routing iterations fully in-block.
__global__ __launch_bounds__(1024) void routing_kernel(
    const float* __restrict__ votes,  // [B][C][R][O]
    float* __restrict__ out)          // [B][C][O]
{
  const int b = blockIdx.x >> 5;
  const int c = blockIdx.x & 31;
  const int t = threadIdx.x;
  const int lane = t & 63;
  const int wave = t >> 6;  // 0..15

  __shared__ float red[16][32];
  __shared__ float verdict_s[32];
  __shared__ float scal[16];
  __shared__ float Ms, Zs;

  // Load the two owned votes rows (each 32 floats, contiguous).
  float v0[32], v1[32];
  const float4* p0 = reinterpret_cast<const float4*>(
      votes + (((size_t)b * C + c) * R + t) * O);
  const float4* p1 = reinterpret_cast<const float4*>(
      votes + (((size_t)b * C + c) * R + t + 1024) * O);
#pragma unroll
  for (int k = 0; k < 8; ++k) {
    float4 u = p0[k];
    v0[4 * k + 0] = u.x; v0[4 * k + 1] = u.y;
    v0[4 * k + 2] = u.z; v0[4 * k + 3] = u.w;
    float4 w = p1[k];
    v1[4 * k + 0] = w.x; v1[4 * k + 1] = w.y;
    v1[4 * k + 2] = w.z; v1[4 * k + 3] = w.w;
  }

  float a0 = 0.0f, a1 = 0.0f;

  for (int iter = 0; iter < 3; ++iter) {
    // ---- block max of agreement ----
    float m = fmaxf(a0, a1);
#pragma unroll
    for (int mask = 32; mask; mask >>= 1) m = fmaxf(m, __shfl_xor(m, mask));
    if (lane == 0) scal[wave] = m;
    __syncthreads();
    if (t == 0) {
      float mm = scal[0];
#pragma unroll
      for (int w = 1; w < 16; ++w) mm = fmaxf(mm, scal[w]);
      Ms = mm;
    }
    __syncthreads();
    const float M = Ms;

    // ---- exp + block sum (softmax denominator) ----
    float e0 = __expf(a0 - M), e1 = __expf(a1 - M);
    float z = e0 + e1;
#pragma unroll
    for (int mask = 32; mask; mask >>= 1) z += __shfl_xor(z, mask);
    if (lane == 0) scal[wave] = z;
    __syncthreads();
    if (t == 0) {
      float zz = 0.0f;
#pragma unroll
      for (int w = 0; w < 16; ++w) zz += scal[w];
      Zs = zz;
    }
    __syncthreads();
    const float Zinv = 1.0f / Zs;

    // ---- S[o] = sum_r e[r] * votes[r][o] ----
    float s[32];
#pragma unroll
    for (int o = 0; o < 32; ++o) s[o] = e0 * v0[o] + e1 * v1[o];
#pragma unroll
    for (int mask = 32; mask; mask >>= 1) {
#pragma unroll
      for (int o = 0; o < 32; ++o) s[o] += __shfl_xor(s[o], mask);
    }
#pragma unroll
    for (int o = 0; o < 32; ++o)
      if (lane == o) red[wave][o] = s[o];
    __syncthreads();

    // ---- wave 0: finish reduction, squash, verdict ----
    if (t < 32) {
      float S = 0.0f;
#pragma unroll
      for (int w = 0; w < 16; ++w) S += red[w][t];
      float summary = S * Zinv;
      float sq = summary * summary;
#pragma unroll
      for (int mask = 16; mask; mask >>= 1) sq += __shfl_xor(sq, mask);
      float scale = sq / ((1.0f + sq) * sqrtf(sq + 1e-8f));
      float vd = summary * scale;
      verdict_s[t] = vd;
      if (iter == 2) out[((size_t)b * C + c) * O + t] = vd;
    }
    __syncthreads();

    // ---- agreement update (dead on last iteration) ----
    if (iter < 2) {
      float u0 = 0.0f, u1 = 0.0f;
#pragma unroll
      for (int o = 0; o < 32; ++o) {
        float vd = verdict_s[o];
        u0 += v0[o] * vd;
        u1 += v1[o] * vd;
      }
      a0 += u0;
      a1 += u1;
    }
    __syncthreads();
  }
}

extern "C" void kernel_launch(void* const* d_in, const int* in_sizes, int n_in,
                              void* d_out, int out_size, void* d_ws, size_t ws_size,
                              hipStream_t stream) {
  const float* x = (const float*)d_in[0];     // [32][2048][16]
  const float* vote = (const float*)d_in[1];  // [2048][32][32][16]
  float* out = (float*)d_out;                 // [32][32][32]
  float* votes = (float*)d_ws;                // [B][C][R][O] = 256 MB

  dim3 g1(R, C);
  votes_kernel<<<g1, 256, 0, stream>>>(x, vote, votes);
  routing_kernel<<<dim3(B * C), 1024, 0, stream>>>(votes, out);
}

// Round 2
// 576.907 us; speedup vs baseline: 1.3020x; 1.3020x over previous
//
#include <hip/hip_runtime.h>
#include <hip/hip_fp16.h>

#define B 32
#define R 2048
#define C 32
#define O 32
#define IN 16

// K1: votes_h[b][c][r][o] = (half) sum_i vote[r][c][o][i] * x[b][r][i]
__global__ __launch_bounds__(256) void votes_kernel(
    const float* __restrict__ x,     // [B][R][IN]
    const float* __restrict__ vote,  // [R][C][O][IN]
    __half* __restrict__ votes_h)    // [B][C][R][O]
{
  const int r0 = blockIdx.x * 2;
  const int c = blockIdx.y;
  const int t = threadIdx.x;
  const int o = t & 31;
  const int bq = t >> 5;  // 0..7

  __shared__ __half tile[32][2][32];  // [b][r][o], 4 KB

#pragma unroll
  for (int r = 0; r < 2; ++r) {
    const float4* vrow = reinterpret_cast<const float4*>(
        vote + (((size_t)(r0 + r) * C + c) * O + o) * IN);
    float4 w0 = vrow[0], w1 = vrow[1], w2 = vrow[2], w3 = vrow[3];
#pragma unroll
    for (int j = 0; j < 4; ++j) {
      int b = bq * 4 + j;
      const float4* xrow = reinterpret_cast<const float4*>(
          x + ((size_t)b * R + r0 + r) * IN);
      float4 x0 = xrow[0], x1 = xrow[1], x2 = xrow[2], x3 = xrow[3];
      float acc =
          w0.x * x0.x + w0.y * x0.y + w0.z * x0.z + w0.w * x0.w +
          w1.x * x1.x + w1.y * x1.y + w1.z * x1.z + w1.w * x1.w +
          w2.x * x2.x + w2.y * x2.y + w2.z * x2.z + w2.w * x2.w +
          w3.x * x3.x + w3.y * x3.y + w3.z * x3.z + w3.w * x3.w;
      tile[b][r][o] = __float2half(acc);
    }
  }
  __syncthreads();

  const int b = t >> 3;
  const int q = t & 7;
  const uint4* src = reinterpret_cast<const uint4*>(tile);
  uint4* dst = reinterpret_cast<uint4*>(
      reinterpret_cast<char*>(votes_h) +
      (((size_t)b * C + c) * R + r0) * O * sizeof(__half));
  dst[q] = src[t];
}

// K2: one block per (b,c); thread t owns rows r=t, r=t+1024.
__global__ __launch_bounds__(1024, 4) void routing_kernel(
    const __half* __restrict__ votes_h,  // [B][C][R][O]
    float* __restrict__ out)             // [B][C][O]
{
  const int b = blockIdx.x >> 5;
  const int c = blockIdx.x & 31;
  const int t = threadIdx.x;
  const int lane = t & 63;
  const int wave = t >> 6;

  __shared__ float red[16][32];
  __shared__ float verdict_s[32];
  __shared__ float scal[16];
  __shared__ float Ms, Zs;

  float v0[32], v1[32];
  {
    const float4* p0 = reinterpret_cast<const float4*>(
        votes_h + (((size_t)b * C + c) * R + t) * O);
    const float4* p1 = reinterpret_cast<const float4*>(
        votes_h + (((size_t)b * C + c) * R + t + 1024) * O);
    float4 r0[4], r1[4];
#pragma unroll
    for (int k = 0; k < 4; ++k) { r0[k] = p0[k]; r1[k] = p1[k]; }
    const __half* h0 = reinterpret_cast<const __half*>(r0);
    const __half* h1 = reinterpret_cast<const __half*>(r1);
#pragma unroll
    for (int k = 0; k < 32; ++k) {
      v0[k] = __half2float(h0[k]);
      v1[k] = __half2float(h1[k]);
    }
  }

  float a0 = 0.0f, a1 = 0.0f;

  for (int iter = 0; iter < 3; ++iter) {
    float m = fmaxf(a0, a1);
#pragma unroll
    for (int mask = 32; mask; mask >>= 1) m = fmaxf(m, __shfl_xor(m, mask));
    if (lane == 0) scal[wave] = m;
    __syncthreads();
    if (t == 0) {
      float mm = scal[0];
#pragma unroll
      for (int w = 1; w < 16; ++w) mm = fmaxf(mm, scal[w]);
      Ms = mm;
    }
    __syncthreads();
    const float M = Ms;

    float e0 = __expf(a0 - M), e1 = __expf(a1 - M);
    {
      float z = e0 + e1;
#pragma unroll
      for (int mask = 32; mask; mask >>= 1) z += __shfl_xor(z, mask);
      if (lane == 0) scal[wave] = z;
    }
    __syncthreads();
    if (t == 0) {
      float zz = 0.0f;
#pragma unroll
      for (int w = 0; w < 16; ++w) zz += scal[w];
      Zs = zz;
    }
    __syncthreads();
    const float Zinv = 1.0f / Zs;

    // S[o] in two 16-wide halves to limit register pressure.
    {
      float s[16];
#pragma unroll
      for (int o = 0; o < 16; ++o) s[o] = e0 * v0[o] + e1 * v1[o];
#pragma unroll
      for (int mask = 32; mask; mask >>= 1) {
#pragma unroll
        for (int o = 0; o < 16; ++o) s[o] += __shfl_xor(s[o], mask);
      }
#pragma unroll
      for (int o = 0; o < 16; ++o)
        if (lane == o) red[wave][o] = s[o];  // lanes 0..15 -> red[w][0..15]
    }
    {
      float s[16];
#pragma unroll
      for (int o = 0; o < 16; ++o) s[o] = e0 * v0[16 + o] + e1 * v1[16 + o];
#pragma unroll
      for (int mask = 32; mask; mask >>= 1) {
#pragma unroll
        for (int o = 0; o < 16; ++o) s[o] += __shfl_xor(s[o], mask);
      }
#pragma unroll
      for (int o = 0; o < 16; ++o)
        if (lane == 16 + o) red[wave][lane] = s[o];  // lanes 16..31 -> red[w][16..31]
    }
    __syncthreads();

    if (t < 32) {
      float S = 0.0f;
#pragma unroll
      for (int w = 0; w < 16; ++w) S += red[w][t];
      float summary = S * Zinv;
      float sq = summary * summary;
#pragma unroll
      for (int mask = 16; mask; mask >>= 1) sq += __shfl_xor(sq, mask);
      float scale = sq / ((1.0f + sq) * sqrtf(sq + 1e-8f));
      float vd = summary * scale;
      verdict_s[t] = vd;
      if (iter == 2) out[((size_t)b * C + c) * O + t] = vd;
    }
    __syncthreads();

    if (iter < 2) {
      float u0 = 0.0f, u1 = 0.0f;
#pragma unroll
      for (int o = 0; o < 32; ++o) {
        float vd = verdict_s[o];
        u0 += v0[o] * vd;
        u1 += v1[o] * vd;
      }
      a0 += u0;
      a1 += u1;
    }
    __syncthreads();
  }
}

extern "C" void kernel_launch(void* const* d_in, const int* in_sizes, int n_in,
                              void* d_out, int out_size, void* d_ws, size_t ws_size,
                              hipStream_t stream) {
  const float* x = (const float*)d_in[0];     // [32][2048][16]
  const float* vote = (const float*)d_in[1];  // [2048][32][32][16]
  float* out = (float*)d_out;                 // [32][32][32]
  __half* votes_h = (__half*)d_ws;            // [B][C][R][O] = 128 MB

  dim3 g1(R / 2, C);
  votes_kernel<<<g1, 256, 0, stream>>>(x, vote, votes_h);
  routing_kernel<<<dim3(B * C), 1024, 0, stream>>>(votes_h, out);
}